// Round 26
// baseline (283.543 us; speedup 1.0000x reference)
//
#include <hip/hip_runtime.h>
#include <hip/hip_bf16.h>

#define NN 384
#define CC 128
#define HH 4
#define DHD 32
#define RR (NN*NN)
#define LN_EPS 1e-5f
#define QSC 0.25503487f          // (1/sqrt(32)) / ln(2)  -> logits in log2 domain
#define LOG2E 1.4426950408889634f

typedef unsigned short u16;
typedef __bf16 bf16x8 __attribute__((ext_vector_type(8)));
typedef float f32x4 __attribute__((ext_vector_type(4)));
typedef float f32x16 __attribute__((ext_vector_type(16)));
typedef unsigned short u16x8 __attribute__((ext_vector_type(8)));
typedef unsigned u32x2v __attribute__((ext_vector_type(2)));
typedef unsigned u32x4v __attribute__((ext_vector_type(4)));

__device__ __forceinline__ u16 f2bf(float f) {
    unsigned u = __float_as_uint(f);
    u += 0x7fffu + ((u >> 16) & 1u);        // RNE
    return (u16)(u >> 16);
}
__device__ __forceinline__ float bf2f(u16 s) { return __uint_as_float(((unsigned)s) << 16); }
__device__ __forceinline__ unsigned cvtpk(float lo, float hi) {
    unsigned r;
    asm("v_cvt_pk_bf16_f32 %0, %1, %2" : "=v"(r) : "v"(lo), "v"(hi));
    return r;
}
// exchange lane-halves: x = [a.lo | b.lo>>hi], y = [a.hi>>lo | b.hi]
__device__ __forceinline__ void swap32(unsigned a, unsigned b, unsigned &x, unsigned &y) {
#if __has_builtin(__builtin_amdgcn_permlane32_swap)
    u32x2v r = __builtin_amdgcn_permlane32_swap(a, b, false, false);
    x = r[0]; y = r[1];
#else
    const bool hi = (threadIdx.x & 32) != 0;
    unsigned tb = (unsigned)__shfl_xor((int)b, 32);
    unsigned ta = (unsigned)__shfl_xor((int)a, 32);
    x = hi ? tb : a;
    y = hi ? b : ta;
#endif
}

// ---------------------------------------------------------------------------
// Kernel W: weights -> FRAGMENT-MAJOR bf16; mask int32 -> bf16 0/1 table.
// ---------------------------------------------------------------------------
__global__ __launch_bounds__(256) void kernW(
    const float* __restrict__ wq, const float* __restrict__ wk, const float* __restrict__ wv,
    const float* __restrict__ wg, const float* __restrict__ wo, const int* __restrict__ mask,
    u16* __restrict__ wqf, u16* __restrict__ wkf, u16* __restrict__ wvf,
    u16* __restrict__ wgf, u16* __restrict__ wof, u16* __restrict__ maskbf)
{
    const int idx = blockIdx.x*256 + threadIdx.x;
    if (idx < 5*16384) {
        const int which = idx >> 14, off = idx & 16383;
        const float* src = which==0?wq: which==1?wk: which==2?wv: which==3?wg: wo;
        u16* dst        = which==0?wqf: which==1?wkf: which==2?wvf: which==3?wgf: wof;
        const int r = off >> 7, c = off & 127;
        const int dt = r >> 4, lc = r & 15;
        const int kt = c >> 5, kg = (c >> 3) & 3, j = c & 7;
        dst[(size_t)((dt*4 + kt)*64 + kg*16 + lc)*8 + j] = f2bf(src[off]);
    } else {
        const int off = idx - 5*16384;
        if (off < RR) maskbf[off] = (mask[off] != 0) ? (u16)0x3F80 : (u16)0;
    }
}

// ---------------------------------------------------------------------------
// Kernel M: per-b all-ones mask flag (enables kernB's no-mask fast path).
// ---------------------------------------------------------------------------
__global__ __launch_bounds__(64) void kernM(
    const int* __restrict__ mask, int* __restrict__ allone)
{
    const int b = blockIdx.x;
    const int lane = threadIdx.x;
    bool ok = true;
    for (int i = lane; i < NN; i += 64) ok &= (mask[b*NN + i] != 0);
    const bool all = __all(ok);
    if (lane == 0) allone[b] = all ? 1 : 0;
}

// ---------------------------------------------------------------------------
// Kernel A: LayerNorm + projections + pair bias, WI-SPLIT across blocks:
// grid 4608 = 2 halves x 2304 row-blocks. Half 0 computes {q, K}; half 1
// computes {V, gate} (each pairs one direct-store + one scattered-store
// projection). LN recomputed per half (pair is L3-resident -> ~free);
// bias written by half 0 only. Halves the per-block serial chain and
// doubles block-level parallelism. Store math identical to r25 PASS.
// ---------------------------------------------------------------------------
__global__ __launch_bounds__(256) void kernA(
    const float* __restrict__ pair, const float* __restrict__ ln_w, const float* __restrict__ ln_b,
    const float* __restrict__ w_bias,
    const u16* __restrict__ wqf, const u16* __restrict__ wkf,
    const u16* __restrict__ wvf, const u16* __restrict__ wgf,
    u16* __restrict__ qbuf, u16* __restrict__ kfrag, u16* __restrict__ vfrag,
    u16* __restrict__ gbuf, float* __restrict__ bfrag)
{
    __shared__ __align__(16) u16 x_tile[64*128];   // 16 KB, XOR-swizzled
    __shared__ __align__(16) u16 w_lds[64*128];    // 16 KB half-table stage

    const int t = threadIdx.x;
    const int gbid = blockIdx.x;
    const int halfsel = gbid / 2304;               // 0: {q,K}  1: {V,g}
    const int bid = gbid % 2304;
    const int base = bid * 64;
    const int b = base / NN;
    const int m0 = base % NN;

    // ---- LayerNorm: 4 lanes per row ----
    const int rl = t >> 2;
    const int lq = t & 3;
    const int grow = base + rl;
    float x[32];
    {
        const float* src = pair + (size_t)grow * CC + lq * 32;
        #pragma unroll
        for (int j = 0; j < 8; j++) {
            f32x4 v = *reinterpret_cast<const f32x4*>(src + j*4);
            #pragma unroll
            for (int e = 0; e < 4; e++) x[j*4+e] = v[e];
        }
    }
    float s = 0.f, sq = 0.f;
    #pragma unroll
    for (int j = 0; j < 32; j++) { s += x[j]; sq += x[j]*x[j]; }
    s  += __shfl_xor(s, 1);  s  += __shfl_xor(s, 2);
    sq += __shfl_xor(sq, 1); sq += __shfl_xor(sq, 2);
    const float mu = s * (1.f/128.f);
    const float rstd = rsqrtf(sq * (1.f/128.f) - mu*mu + LN_EPS);
    float pb[4] = {0.f,0.f,0.f,0.f};
    #pragma unroll
    for (int j = 0; j < 32; j++) {
        const int c = lq*32 + j;
        float xh = (x[j] - mu) * rstd * ln_w[c] + ln_b[c];
        x[j] = xh;
        #pragma unroll
        for (int h = 0; h < 4; h++) pb[h] += xh * w_bias[h*CC + c];
    }
    #pragma unroll
    for (int j8 = 0; j8 < 4; j8++) {
        u16x8 pk;
        #pragma unroll
        for (int e = 0; e < 8; e++) pk[e] = f2bf(x[j8*8 + e]);
        unsigned addr = (unsigned)(rl*256 + (lq*32 + j8*8)*2) ^ (unsigned)((rl & 7) << 4);
        *reinterpret_cast<u16x8*>(reinterpret_cast<char*>(x_tile) + addr) = pk;
    }
    // pair bias (f32, log2-domain) -> fragment-major bfrag  (half 0 only)
    if (halfsel == 0) {
        #pragma unroll
        for (int h = 0; h < 4; h++) {
            float v = pb[h];
            v += __shfl_xor(v, 1); v += __shfl_xor(v, 2);
            if (lq == h) {
                const int qq = b;                 // query index = pair's first idx
                const int kk = m0 + rl;           // key index = pair's second idx
                const int qtile = qq >> 5, l31q = qq & 31;
                const int ktb = kk >> 5, rb = kk & 31;
                const int rgb = rb >> 3, hfb = (rb >> 2) & 1, ib = rb & 3;
                bfrag[((((size_t)h*12 + qtile)*12 + ktb)*4 + rgb)*256 + (hfb*32 + l31q)*4 + ib]
                    = v * LOG2E;
            }
        }
    }

    const int wv = t >> 6;
    const int lane = t & 63;
    const int lc = lane & 15;
    const int kg = lane >> 4;

    bf16x8 afr[4];
    {
        const int rA = wv*16 + lc;
        #pragma unroll
        for (int kt = 0; kt < 4; kt++) {
            unsigned addr = (unsigned)(rA*256 + (kt*32 + kg*8)*2) ^ (unsigned)((rA & 7) << 4);
            afr[kt] = *reinterpret_cast<const bf16x8*>(reinterpret_cast<const char*>(x_tile) + addr);
        }
    }

    const u16* Wf[4] = {wqf, wkf, wvf, wgf};
    #pragma unroll
    for (int wi2 = 0; wi2 < 2; wi2++) {
        const int wi = halfsel*2 + wi2;            // half0: q,K  half1: V,g
        const u16* WF = Wf[wi];
        #pragma unroll
        for (int hf2 = 0; hf2 < 2; hf2++) {
            __syncthreads();                   // w_lds free (prev half readers done)
            #pragma unroll
            for (int i = 0; i < 4; i++) {
                const int chunk = i*256 + t;   // 1024 x 16B identity copy (half table)
                *reinterpret_cast<u16x8*>(w_lds + (size_t)chunk*8) =
                    *reinterpret_cast<const u16x8*>(WF + (size_t)(hf2*1024 + chunk)*8);
            }
            __syncthreads();

            #pragma unroll
            for (int ldt = 0; ldt < 4; ldt++) {
                const int dt = hf2*4 + ldt;
                f32x4 acc = {0.f, 0.f, 0.f, 0.f};
                #pragma unroll
                for (int kt = 0; kt < 4; kt++) {
                    const bf16x8 bfr = *reinterpret_cast<const bf16x8*>(
                        w_lds + (size_t)((ldt*4 + kt)*64 + lane)*8);  // conflict-free
                    acc = __builtin_amdgcn_mfma_f32_16x16x32_bf16(afr[kt], bfr, acc, 0, 0, 0);
                }
                if (wi == 1) {
                    // K -> kfrag (direct scattered stores)
                    #pragma unroll
                    for (int i = 0; i < 4; i++) {
                        const int keyl = m0 + wv*16 + kg*4 + i;
                        const int d = dt*16 + lc;
                        const int h = d >> 5, d32 = d & 31, mf = d32 >> 4, dd = d32 & 15;
                        const int hf = dd >> 3, j = dd & 7;
                        kfrag[(((size_t)(b*HH + h)*12 + (keyl >> 5))*2 + mf)*512
                              + (hf*32 + (keyl & 31))*8 + j] = f2bf(acc[i]);
                    }
                } else if (wi == 2) {
                    // V -> vfrag
                    #pragma unroll
                    for (int i = 0; i < 4; i++) {
                        const int keyl = m0 + wv*16 + kg*4 + i;
                        const int d = dt*16 + lc;
                        const int h = d >> 5, d32 = d & 31;
                        const int r = keyl & 31, mf = r >> 4, rr = r & 15;
                        const int hf = rr >> 3, j = rr & 7;
                        vfrag[(((size_t)(b*HH + h)*12 + (keyl >> 5))*2 + mf)*512
                              + (hf*32 + d32)*8 + j] = f2bf(acc[i]);
                    }
                } else {
                    u16* dst = (wi == 0) ? qbuf : gbuf;
                    #pragma unroll
                    for (int i = 0; i < 4; i++) {
                        float v = acc[i];
                        if (wi == 0) v *= QSC;                       // fold softmax scale (log2)
                        if (wi == 3) v = 1.f / (1.f + __expf(-v));   // sigmoid gate
                        dst[(size_t)(base + wv*16 + kg*4 + i) * CC + dt*16 + lc] = f2bf(v);
                    }
                }
            }
        }
    }
}

// ---------------------------------------------------------------------------
// Kernel B: fused streaming attention, 32x32x16 MFMA. Grid 4608 = 4 h x 12 qt
// x 96 bgroup; block = 256 thr = 4 waves sharing ONE (h, qtile): the 48 KB f32
// bias slice is staged into LDS ONCE per block (1 barrier, read-only after) ->
// bias L2 traffic /4. Wave w handles b = bgroup*4 + w. Row-sums accumulate on
// the idle MATRIX pipe via ones-B MFMA (lane-local result, no epilogue shfl).
// K ring 2-deep, V hoisted. bid mod 8 = bgroup mod 8 -> K/V XCD partitioning.
// ---------------------------------------------------------------------------
__global__ __launch_bounds__(256) void kernB(
    const u16* __restrict__ qbuf, const u16* __restrict__ kfrag, const u16* __restrict__ vfrag,
    const float* __restrict__ bfrag, const u16* __restrict__ maskbf,
    const int* __restrict__ allone, u16* __restrict__ wagbuf)
{
    __shared__ __align__(16) float blds[12*1024];   // 48 KB bias slice

    const int t = threadIdx.x;
    const int w = t >> 6;
    const int lane = t & 63;
    const int l31 = lane & 31;
    const int half = (lane >> 5) & 1;

    const int bid = blockIdx.x;
    const int h = bid / 1152;           // 0..3
    const int r2 = bid % 1152;
    const int qt12 = r2 / 96;           // 0..11
    const int bgroup = r2 % 96;         // 0..95  (bid mod 8 == bgroup mod 8)
    const int b = bgroup*4 + w;         // wave's batch row
    const int qt = qt12 * 32;           // block's 32-q tile

    // ---- stage bias slice (h, qt12) into LDS: 12288 f32, coalesced ----
    {
        const float* bsrc = bfrag + ((size_t)(h*12 + qt12)*12)*1024;
        #pragma unroll
        for (int i = 0; i < 12; i++) {
            const int idx = i*256 + t;
            *reinterpret_cast<f32x4*>(blds + (size_t)idx*4) =
                *reinterpret_cast<const f32x4*>(bsrc + (size_t)idx*4);
        }
    }
    __syncthreads();                    // blds read-only below

    const bool am = (allone[b] != 0);

    const size_t qoff = (size_t)(b*NN + qt + l31)*CC + h*32 + 8*half;
    const bf16x8 aq_lo = *reinterpret_cast<const bf16x8*>(qbuf + qoff);
    const bf16x8 aq_hi = *reinterpret_cast<const bf16x8*>(qbuf + qoff + 16);

    const u16* kfb = kfrag + ((size_t)(b*HH + h)*12)*1024;
    const u16* vfb = vfrag + ((size_t)(b*HH + h)*12)*1024;
    const u16* mbase = maskbf + (size_t)b*NN + 4*half;

    bf16x8 ones;
    #pragma unroll
    for (int e = 0; e < 8; e++) ones[e] = (__bf16)1.0f;

    // ---- prologue: K ring 2-deep ----
    bf16x8 klo[2], khi[2];
    #pragma unroll
    for (int i = 0; i < 2; i++) {
        klo[i] = *reinterpret_cast<const bf16x8*>(kfb + i*1024 + lane*8);
        khi[i] = *reinterpret_cast<const bf16x8*>(kfb + i*1024 + 512 + lane*8);
    }

    f32x16 acc, acc_sum;
    #pragma unroll
    for (int i = 0; i < 16; i++) { acc[i] = 0.f; acc_sum[i] = 0.f; }

    #pragma unroll
    for (int kt = 0; kt < 12; kt++) {
        const int cs = kt & 1;
        // V for this chunk (L2-warm), issued before the MFMAs
        const bf16x8 vf1 = *reinterpret_cast<const bf16x8*>(vfb + kt*1024 + lane*8);
        const bf16x8 vf2 = *reinterpret_cast<const bf16x8*>(vfb + kt*1024 + 512 + lane*8);

        // bias C-in from LDS (ds_read_b128 x4)
        f32x16 S;
        {
            const float* bp = blds + kt*1024 + lane*4;
            #pragma unroll
            for (int rg = 0; rg < 4; rg++) {
                const f32x4 cb = *reinterpret_cast<const f32x4*>(bp + rg*256);
                S[4*rg+0] = cb[0]; S[4*rg+1] = cb[1]; S[4*rg+2] = cb[2]; S[4*rg+3] = cb[3];
            }
        }
        // QK^T for kt
        S = __builtin_amdgcn_mfma_f32_32x32x16_bf16(klo[cs], aq_lo, S, 0, 0, 0);
        S = __builtin_amdgcn_mfma_f32_32x32x16_bf16(khi[cs], aq_hi, S, 0, 0, 0);

        // refill K slot cs with chunk kt+2
        if (kt < 10) {
            klo[cs] = *reinterpret_cast<const bf16x8*>(kfb + (kt+2)*1024 + lane*8);
            khi[cs] = *reinterpret_cast<const bf16x8*>(kfb + (kt+2)*1024 + 512 + lane*8);
        }

        // exp2 [*mask]  (sum deferred to the matrix pipe)
        if (am) {
            #pragma unroll
            for (int i = 0; i < 16; i++) S[i] = __builtin_exp2f(S[i]);
        } else {
            const int key0 = kt*32;
            #pragma unroll
            for (int rg = 0; rg < 4; rg++) {
                const uint2 mp = *reinterpret_cast<const uint2*>(mbase + key0 + 8*rg);
                float m[4];
                m[0] = __uint_as_float(mp.x << 16);
                m[1] = __uint_as_float(mp.x & 0xFFFF0000u);
                m[2] = __uint_as_float(mp.y << 16);
                m[3] = __uint_as_float(mp.y & 0xFFFF0000u);
                #pragma unroll
                for (int i = 0; i < 4; i++)
                    S[4*rg+i] = __builtin_exp2f(S[4*rg+i]) * m[i];
            }
        }
        // pack + in-register half-swap -> PV A-frags
        unsigned a01 = cvtpk(S[0],S[1]),   a23 = cvtpk(S[2],S[3]);
        unsigned b01 = cvtpk(S[4],S[5]),   b23 = cvtpk(S[6],S[7]);
        unsigned c01 = cvtpk(S[8],S[9]),   c23 = cvtpk(S[10],S[11]);
        unsigned d01 = cvtpk(S[12],S[13]), d23 = cvtpk(S[14],S[15]);
        unsigned w0,w1,w2,w3,w4,w5,w6,w7;
        swap32(a01, b01, w0, w2);
        swap32(a23, b23, w1, w3);
        swap32(c01, d01, w4, w6);
        swap32(c23, d23, w5, w7);
        const u32x4v A1v = {w0,w1,w2,w3};
        const u32x4v A2v = {w4,w5,w6,w7};
        const bf16x8 A1 = __builtin_bit_cast(bf16x8, A1v);
        const bf16x8 A2 = __builtin_bit_cast(bf16x8, A2v);
        // PV + row-sum accumulate (all on matrix pipe)
        acc = __builtin_amdgcn_mfma_f32_32x32x16_bf16(A1, vf1, acc, 0, 0, 0);
        acc = __builtin_amdgcn_mfma_f32_32x32x16_bf16(A2, vf2, acc, 0, 0, 0);
        acc_sum = __builtin_amdgcn_mfma_f32_32x32x16_bf16(A1, ones, acc_sum, 0, 0, 0);
        acc_sum = __builtin_amdgcn_mfma_f32_32x32x16_bf16(A2, ones, acc_sum, 0, 0, 0);
    }

    // epilogue: acc row q=(r&3)+8*(r>>2)+4*half, col d=l31; acc_sum[r] is the
    // row-sum (identical across lanes) -> per-lane normalize, no shfl.
    #pragma unroll
    for (int r = 0; r < 16; r++) {
        const int q_r = (r & 3) + 8*(r >> 2) + 4*half;
        wagbuf[(size_t)(b*NN + qt + q_r)*CC + h*32 + l31] = f2bf(acc[r] / acc_sum[r]);
    }
}

// ---------------------------------------------------------------------------
// Kernel C: out = (wag * gate) . w_o^T. Barrier-free: a_tile rows wave-private;
// w_o fragment-major (coalesced loads).
// ---------------------------------------------------------------------------
__global__ __launch_bounds__(256) void kernC(
    const u16* __restrict__ wag, const u16* __restrict__ gbuf,
    const u16* __restrict__ wof, float* __restrict__ out)
{
    __shared__ __align__(16) u16 a_tile[64*128];

    const int t = threadIdx.x;
    const int base = blockIdx.x * 64;

    {
        const int rl = t >> 2;
        const int lq = t & 3;
        const u16* src  = wag  + (size_t)(base + rl)*CC + lq*32;
        const u16* gsrc = gbuf + (size_t)(base + rl)*CC + lq*32;
        #pragma unroll
        for (int j8 = 0; j8 < 4; j8++) {
            u16x8 v = *reinterpret_cast<const u16x8*>(src + j8*8);
            u16x8 g = *reinterpret_cast<const u16x8*>(gsrc + j8*8);
            u16x8 pk;
            #pragma unroll
            for (int e = 0; e < 8; e++) pk[e] = f2bf(bf2f(v[e]) * bf2f(g[e]));
            unsigned addr = (unsigned)(rl*256 + (lq*32 + j8*8)*2) ^ (unsigned)((rl & 7) << 4);
            *reinterpret_cast<u16x8*>(reinterpret_cast<char*>(a_tile) + addr) = pk;
        }
    }
    // no barrier: each wave reads only the 16 rows it wrote

    const int wv = t >> 6;
    const int lane = t & 63;
    const int lc = lane & 15;
    const int kg = lane >> 4;

    bf16x8 afr[4];
    {
        const int rA = wv*16 + lc;
        #pragma unroll
        for (int kt = 0; kt < 4; kt++) {
            unsigned addr = (unsigned)(rA*256 + (kt*32 + kg*8)*2) ^ (unsigned)((rA & 7) << 4);
            afr[kt] = *reinterpret_cast<const bf16x8*>(reinterpret_cast<const char*>(a_tile) + addr);
        }
    }
    #pragma unroll
    for (int et = 0; et < 8; et++) {
        f32x4 acc = {0.f,0.f,0.f,0.f};
        #pragma unroll
        for (int kt = 0; kt < 4; kt++) {
            const bf16x8 bw = *reinterpret_cast<const bf16x8*>(
                wof + (size_t)((et*4 + kt)*64 + lane)*8);
            acc = __builtin_amdgcn_mfma_f32_16x16x32_bf16(afr[kt], bw, acc, 0, 0, 0);
        }
        #pragma unroll
        for (int i = 0; i < 4; i++)
            out[(size_t)(base + wv*16 + kg*4 + i)*CC + et*16 + lc] = acc[i];
    }
}

extern "C" void kernel_launch(void* const* d_in, const int* in_sizes, int n_in,
                              void* d_out, int out_size, void* d_ws, size_t ws_size,
                              hipStream_t stream)
{
    const float* pair  = (const float*)d_in[0];
    const int*   mask  = (const int*)d_in[1];
    const float* ln_w  = (const float*)d_in[2];
    const float* ln_b  = (const float*)d_in[3];
    const float* w_bias= (const float*)d_in[4];
    const float* w_q   = (const float*)d_in[5];
    const float* w_k   = (const float*)d_in[6];
    const float* w_v   = (const float*)d_in[7];
    const float* w_g   = (const float*)d_in[8];
    const float* w_o   = (const float*)d_in[9];
    float* out = (float*)d_out;

    char* ws = (char*)d_ws;
    const size_t SZ = (size_t)RR * CC * 2;       // 37,748,736
    u16* qbuf  = (u16*)(ws);
    u16* kfrag = (u16*)(ws + SZ);
    u16* vfrag = (u16*)(ws + 2*SZ);
    u16* gbuf  = (u16*)(ws + 3*SZ);
    float* bfrag = (float*)(ws + 4*SZ);                         // 2,359,296
    char* p = ws + 4*SZ + (size_t)4*RR*4;
    u16* wof  = (u16*)(p);            p += (size_t)CC*CC*2;     // 32 KiB each
    u16* wqf  = (u16*)(p);            p += (size_t)CC*CC*2;
    u16* wkf  = (u16*)(p);            p += (size_t)CC*CC*2;
    u16* wvf  = (u16*)(p);            p += (size_t)CC*CC*2;
    u16* wgf  = (u16*)(p);            p += (size_t)CC*CC*2;
    u16* maskbf = (u16*)(p);          p += (size_t)RR*2;        // 288 KiB
    int* allone = (int*)(p);          p += (size_t)NN*4;        // 1.5 KiB
    const size_t used = (size_t)(p - ws);
    u16* wagbuf = (ws_size >= used + SZ) ? (u16*)(p) : qbuf;

    kernW<<<dim3(896), dim3(256), 0, stream>>>(w_q, w_k, w_v, w_g, w_o, mask,
        wqf, wkf, wvf, wgf, wof, maskbf);
    kernM<<<dim3(NN), dim3(64), 0, stream>>>(mask, allone);
    kernA<<<dim3(4608), dim3(256), 0, stream>>>(pair, ln_w, ln_b, w_bias,
        wqf, wkf, wvf, wgf, qbuf, kfrag, vfrag, gbuf, bfrag);
    kernB<<<dim3(4608), dim3(256), 0, stream>>>(qbuf, kfrag, vfrag, bfrag, maskbf, allone, wagbuf);
    kernC<<<dim3(RR/64), dim3(256), 0, stream>>>(wagbuf, gbuf, wof, out);
}

// Round 27
// 220.693 us; speedup vs baseline: 1.2848x; 1.2848x over previous
//
#include <hip/hip_runtime.h>
#include <hip/hip_bf16.h>

#define NN 384
#define CC 128
#define HH 4
#define DHD 32
#define RR (NN*NN)
#define LN_EPS 1e-5f
#define QSC 0.25503487f          // (1/sqrt(32)) / ln(2)  -> logits in log2 domain
#define LOG2E 1.4426950408889634f

typedef unsigned short u16;
typedef __bf16 bf16x8 __attribute__((ext_vector_type(8)));
typedef float f32x4 __attribute__((ext_vector_type(4)));
typedef float f32x16 __attribute__((ext_vector_type(16)));
typedef unsigned short u16x8 __attribute__((ext_vector_type(8)));
typedef unsigned u32x2v __attribute__((ext_vector_type(2)));
typedef unsigned u32x4v __attribute__((ext_vector_type(4)));

__device__ __forceinline__ u16 f2bf(float f) {
    unsigned u = __float_as_uint(f);
    u += 0x7fffu + ((u >> 16) & 1u);        // RNE
    return (u16)(u >> 16);
}
__device__ __forceinline__ float bf2f(u16 s) { return __uint_as_float(((unsigned)s) << 16); }
__device__ __forceinline__ unsigned cvtpk(float lo, float hi) {
    unsigned r;
    asm("v_cvt_pk_bf16_f32 %0, %1, %2" : "=v"(r) : "v"(lo), "v"(hi));
    return r;
}
// exchange lane-halves: x = [a.lo | b.lo>>hi], y = [a.hi>>lo | b.hi]
__device__ __forceinline__ void swap32(unsigned a, unsigned b, unsigned &x, unsigned &y) {
#if __has_builtin(__builtin_amdgcn_permlane32_swap)
    u32x2v r = __builtin_amdgcn_permlane32_swap(a, b, false, false);
    x = r[0]; y = r[1];
#else
    const bool hi = (threadIdx.x & 32) != 0;
    unsigned tb = (unsigned)__shfl_xor((int)b, 32);
    unsigned ta = (unsigned)__shfl_xor((int)a, 32);
    x = hi ? tb : a;
    y = hi ? b : ta;
#endif
}

// ---------------------------------------------------------------------------
// Kernel W: weights -> FRAGMENT-MAJOR bf16; mask int32 -> bf16 0/1 table.
// Blocks >= 896 compute the per-b all-ones mask flags (kernM folded in).
// ---------------------------------------------------------------------------
__global__ __launch_bounds__(256) void kernW(
    const float* __restrict__ wq, const float* __restrict__ wk, const float* __restrict__ wv,
    const float* __restrict__ wg, const float* __restrict__ wo, const int* __restrict__ mask,
    u16* __restrict__ wqf, u16* __restrict__ wkf, u16* __restrict__ wvf,
    u16* __restrict__ wgf, u16* __restrict__ wof, u16* __restrict__ maskbf,
    int* __restrict__ allone)
{
    const int bid = blockIdx.x;
    if (bid >= 896) {
        // allone flags: 96 blocks x 4 waves, wave handles one b
        const int w = threadIdx.x >> 6;
        const int lane = threadIdx.x & 63;
        const int b = (bid - 896)*4 + w;
        bool ok = true;
        for (int i = lane; i < NN; i += 64) ok &= (mask[b*NN + i] != 0);
        const bool all = __all(ok);
        if (lane == 0) allone[b] = all ? 1 : 0;
        return;
    }
    const int idx = bid*256 + threadIdx.x;
    if (idx < 5*16384) {
        const int which = idx >> 14, off = idx & 16383;
        const float* src = which==0?wq: which==1?wk: which==2?wv: which==3?wg: wo;
        u16* dst        = which==0?wqf: which==1?wkf: which==2?wvf: which==3?wgf: wof;
        const int r = off >> 7, c = off & 127;
        const int dt = r >> 4, lc = r & 15;
        const int kt = c >> 5, kg = (c >> 3) & 3, j = c & 7;
        dst[(size_t)((dt*4 + kt)*64 + kg*16 + lc)*8 + j] = f2bf(src[off]);
    } else {
        const int off = idx - 5*16384;
        if (off < RR) maskbf[off] = (mask[off] != 0) ? (u16)0x3F80 : (u16)0;
    }
}

// ---------------------------------------------------------------------------
// Kernel A: LayerNorm + q/k/v/gate projections + pair bias.
// Weight table staged per-wi into LDS (identity copy of the fragment-major
// layout; coalesced 16B, conflict-free reads) to amortize L2 latency per
// BLOCK instead of per wave. All output stores are direct global stores
// (r21/r23 passing path).
// ---------------------------------------------------------------------------
__global__ __launch_bounds__(256) void kernA(
    const float* __restrict__ pair, const float* __restrict__ ln_w, const float* __restrict__ ln_b,
    const float* __restrict__ w_bias,
    const u16* __restrict__ wqf, const u16* __restrict__ wkf,
    const u16* __restrict__ wvf, const u16* __restrict__ wgf,
    u16* __restrict__ qbuf, u16* __restrict__ kfrag, u16* __restrict__ vfrag,
    u16* __restrict__ gbuf, float* __restrict__ bfrag)
{
    __shared__ __align__(16) u16 x_tile[64*128];   // 16 KB, XOR-swizzled
    __shared__ __align__(16) u16 w_lds[128*128];   // 32 KB weight stage

    const int t = threadIdx.x;
    const int bid = blockIdx.x;
    const int base = bid * 64;
    const int b = base / NN;
    const int m0 = base % NN;

    // ---- LayerNorm: 4 lanes per row ----
    const int rl = t >> 2;
    const int lq = t & 3;
    const int grow = base + rl;
    float x[32];
    {
        const float* src = pair + (size_t)grow * CC + lq * 32;
        #pragma unroll
        for (int j = 0; j < 8; j++) {
            f32x4 v = *reinterpret_cast<const f32x4*>(src + j*4);
            #pragma unroll
            for (int e = 0; e < 4; e++) x[j*4+e] = v[e];
        }
    }
    float s = 0.f, sq = 0.f;
    #pragma unroll
    for (int j = 0; j < 32; j++) { s += x[j]; sq += x[j]*x[j]; }
    s  += __shfl_xor(s, 1);  s  += __shfl_xor(s, 2);
    sq += __shfl_xor(sq, 1); sq += __shfl_xor(sq, 2);
    const float mu = s * (1.f/128.f);
    const float rstd = rsqrtf(sq * (1.f/128.f) - mu*mu + LN_EPS);
    float pb[4] = {0.f,0.f,0.f,0.f};
    #pragma unroll
    for (int j = 0; j < 32; j++) {
        const int c = lq*32 + j;
        float xh = (x[j] - mu) * rstd * ln_w[c] + ln_b[c];
        x[j] = xh;
        #pragma unroll
        for (int h = 0; h < 4; h++) pb[h] += xh * w_bias[h*CC + c];
    }
    #pragma unroll
    for (int j8 = 0; j8 < 4; j8++) {
        u16x8 pk;
        #pragma unroll
        for (int e = 0; e < 8; e++) pk[e] = f2bf(x[j8*8 + e]);
        unsigned addr = (unsigned)(rl*256 + (lq*32 + j8*8)*2) ^ (unsigned)((rl & 7) << 4);
        *reinterpret_cast<u16x8*>(reinterpret_cast<char*>(x_tile) + addr) = pk;
    }
    // pair bias (f32, log2-domain) -> fragment-major bfrag
    #pragma unroll
    for (int h = 0; h < 4; h++) {
        float v = pb[h];
        v += __shfl_xor(v, 1); v += __shfl_xor(v, 2);
        if (lq == h) {
            const int qq = b;                 // query index = pair's first idx
            const int kk = m0 + rl;           // key index = pair's second idx
            const int qtile = qq >> 5, l31q = qq & 31;
            const int ktb = kk >> 5, rb = kk & 31;
            const int rgb = rb >> 3, hfb = (rb >> 2) & 1, ib = rb & 3;
            bfrag[((((size_t)h*12 + qtile)*12 + ktb)*4 + rgb)*256 + (hfb*32 + l31q)*4 + ib]
                = v * LOG2E;
        }
    }

    const int wv = t >> 6;
    const int lane = t & 63;
    const int lc = lane & 15;
    const int kg = lane >> 4;

    bf16x8 afr[4];
    {
        const int rA = wv*16 + lc;
        #pragma unroll
        for (int kt = 0; kt < 4; kt++) {
            unsigned addr = (unsigned)(rA*256 + (kt*32 + kg*8)*2) ^ (unsigned)((rA & 7) << 4);
            afr[kt] = *reinterpret_cast<const bf16x8*>(reinterpret_cast<const char*>(x_tile) + addr);
        }
    }

    const u16* Wf[4] = {wqf, wkf, wvf, wgf};
    #pragma unroll
    for (int wi = 0; wi < 4; wi++) {
        const u16* WF = Wf[wi];
        __syncthreads();                       // w_lds free (prev wi readers done)
        #pragma unroll
        for (int i = 0; i < 8; i++) {
            const int chunk = i*256 + t;       // 2048 x 16B identity copy
            *reinterpret_cast<u16x8*>(w_lds + (size_t)chunk*8) =
                *reinterpret_cast<const u16x8*>(WF + (size_t)chunk*8);
        }
        __syncthreads();

        #pragma unroll
        for (int dt = 0; dt < 8; dt++) {
            f32x4 acc = {0.f, 0.f, 0.f, 0.f};
            #pragma unroll
            for (int kt = 0; kt < 4; kt++) {
                const bf16x8 bfr = *reinterpret_cast<const bf16x8*>(
                    w_lds + (size_t)((dt*4 + kt)*64 + lane)*8);  // conflict-free
                acc = __builtin_amdgcn_mfma_f32_16x16x32_bf16(afr[kt], bfr, acc, 0, 0, 0);
            }
            if (wi == 1) {
                // K -> kfrag (direct scattered stores)
                #pragma unroll
                for (int i = 0; i < 4; i++) {
                    const int keyl = m0 + wv*16 + kg*4 + i;
                    const int d = dt*16 + lc;
                    const int h = d >> 5, d32 = d & 31, mf = d32 >> 4, dd = d32 & 15;
                    const int hf = dd >> 3, j = dd & 7;
                    kfrag[(((size_t)(b*HH + h)*12 + (keyl >> 5))*2 + mf)*512
                          + (hf*32 + (keyl & 31))*8 + j] = f2bf(acc[i]);
                }
            } else if (wi == 2) {
                // V -> vfrag
                #pragma unroll
                for (int i = 0; i < 4; i++) {
                    const int keyl = m0 + wv*16 + kg*4 + i;
                    const int d = dt*16 + lc;
                    const int h = d >> 5, d32 = d & 31;
                    const int r = keyl & 31, mf = r >> 4, rr = r & 15;
                    const int hf = rr >> 3, j = rr & 7;
                    vfrag[(((size_t)(b*HH + h)*12 + (keyl >> 5))*2 + mf)*512
                          + (hf*32 + d32)*8 + j] = f2bf(acc[i]);
                }
            } else {
                u16* dst = (wi == 0) ? qbuf : gbuf;
                #pragma unroll
                for (int i = 0; i < 4; i++) {
                    float v = acc[i];
                    if (wi == 0) v *= QSC;                       // fold softmax scale (log2)
                    if (wi == 3) v = 1.f / (1.f + __expf(-v));   // sigmoid gate
                    dst[(size_t)(base + wv*16 + kg*4 + i) * CC + dt*16 + lc] = f2bf(v);
                }
            }
        }
    }
}

// ---------------------------------------------------------------------------
// Kernel B: fused streaming attention, 32x32x16 MFMA. Grid 4608 = 4 h x 12 qt
// x 96 bgroup; block = 256 thr = 4 waves sharing ONE (h, qtile): the 48 KB f32
// bias slice is staged into LDS ONCE per block (1 barrier, read-only after) ->
// bias L2 traffic /4. Wave w handles b = bgroup*4 + w. Row-sums accumulate on
// the idle MATRIX pipe via ones-B MFMA (lane-local result, no epilogue shfl).
// K ring 2-deep, V hoisted. bid mod 8 = bgroup mod 8 -> K/V XCD partitioning.
// ---------------------------------------------------------------------------
__global__ __launch_bounds__(256) void kernB(
    const u16* __restrict__ qbuf, const u16* __restrict__ kfrag, const u16* __restrict__ vfrag,
    const float* __restrict__ bfrag, const u16* __restrict__ maskbf,
    const int* __restrict__ allone, u16* __restrict__ wagbuf)
{
    __shared__ __align__(16) float blds[12*1024];   // 48 KB bias slice

    const int t = threadIdx.x;
    const int w = t >> 6;
    const int lane = t & 63;
    const int l31 = lane & 31;
    const int half = (lane >> 5) & 1;

    const int bid = blockIdx.x;
    const int h = bid / 1152;           // 0..3
    const int r2 = bid % 1152;
    const int qt12 = r2 / 96;           // 0..11
    const int bgroup = r2 % 96;         // 0..95  (bid mod 8 == bgroup mod 8)
    const int b = bgroup*4 + w;         // wave's batch row
    const int qt = qt12 * 32;           // block's 32-q tile

    // ---- stage bias slice (h, qt12) into LDS: 12288 f32, coalesced ----
    {
        const float* bsrc = bfrag + ((size_t)(h*12 + qt12)*12)*1024;
        #pragma unroll
        for (int i = 0; i < 12; i++) {
            const int idx = i*256 + t;
            *reinterpret_cast<f32x4*>(blds + (size_t)idx*4) =
                *reinterpret_cast<const f32x4*>(bsrc + (size_t)idx*4);
        }
    }
    __syncthreads();                    // blds read-only below

    const bool am = (allone[b] != 0);

    const size_t qoff = (size_t)(b*NN + qt + l31)*CC + h*32 + 8*half;
    const bf16x8 aq_lo = *reinterpret_cast<const bf16x8*>(qbuf + qoff);
    const bf16x8 aq_hi = *reinterpret_cast<const bf16x8*>(qbuf + qoff + 16);

    const u16* kfb = kfrag + ((size_t)(b*HH + h)*12)*1024;
    const u16* vfb = vfrag + ((size_t)(b*HH + h)*12)*1024;
    const u16* mbase = maskbf + (size_t)b*NN + 4*half;

    bf16x8 ones;
    #pragma unroll
    for (int e = 0; e < 8; e++) ones[e] = (__bf16)1.0f;

    // ---- prologue: K ring 2-deep ----
    bf16x8 klo[2], khi[2];
    #pragma unroll
    for (int i = 0; i < 2; i++) {
        klo[i] = *reinterpret_cast<const bf16x8*>(kfb + i*1024 + lane*8);
        khi[i] = *reinterpret_cast<const bf16x8*>(kfb + i*1024 + 512 + lane*8);
    }

    f32x16 acc, acc_sum;
    #pragma unroll
    for (int i = 0; i < 16; i++) { acc[i] = 0.f; acc_sum[i] = 0.f; }

    #pragma unroll
    for (int kt = 0; kt < 12; kt++) {
        const int cs = kt & 1;
        // V for this chunk (L2-warm), issued before the MFMAs
        const bf16x8 vf1 = *reinterpret_cast<const bf16x8*>(vfb + kt*1024 + lane*8);
        const bf16x8 vf2 = *reinterpret_cast<const bf16x8*>(vfb + kt*1024 + 512 + lane*8);

        // bias C-in from LDS (ds_read_b128 x4)
        f32x16 S;
        {
            const float* bp = blds + kt*1024 + lane*4;
            #pragma unroll
            for (int rg = 0; rg < 4; rg++) {
                const f32x4 cb = *reinterpret_cast<const f32x4*>(bp + rg*256);
                S[4*rg+0] = cb[0]; S[4*rg+1] = cb[1]; S[4*rg+2] = cb[2]; S[4*rg+3] = cb[3];
            }
        }
        // QK^T for kt
        S = __builtin_amdgcn_mfma_f32_32x32x16_bf16(klo[cs], aq_lo, S, 0, 0, 0);
        S = __builtin_amdgcn_mfma_f32_32x32x16_bf16(khi[cs], aq_hi, S, 0, 0, 0);

        // refill K slot cs with chunk kt+2
        if (kt < 10) {
            klo[cs] = *reinterpret_cast<const bf16x8*>(kfb + (kt+2)*1024 + lane*8);
            khi[cs] = *reinterpret_cast<const bf16x8*>(kfb + (kt+2)*1024 + 512 + lane*8);
        }

        // exp2 [*mask]  (sum deferred to the matrix pipe)
        if (am) {
            #pragma unroll
            for (int i = 0; i < 16; i++) S[i] = __builtin_exp2f(S[i]);
        } else {
            const int key0 = kt*32;
            #pragma unroll
            for (int rg = 0; rg < 4; rg++) {
                const uint2 mp = *reinterpret_cast<const uint2*>(mbase + key0 + 8*rg);
                float m[4];
                m[0] = __uint_as_float(mp.x << 16);
                m[1] = __uint_as_float(mp.x & 0xFFFF0000u);
                m[2] = __uint_as_float(mp.y << 16);
                m[3] = __uint_as_float(mp.y & 0xFFFF0000u);
                #pragma unroll
                for (int i = 0; i < 4; i++)
                    S[4*rg+i] = __builtin_exp2f(S[4*rg+i]) * m[i];
            }
        }
        // pack + in-register half-swap -> PV A-frags
        unsigned a01 = cvtpk(S[0],S[1]),   a23 = cvtpk(S[2],S[3]);
        unsigned b01 = cvtpk(S[4],S[5]),   b23 = cvtpk(S[6],S[7]);
        unsigned c01 = cvtpk(S[8],S[9]),   c23 = cvtpk(S[10],S[11]);
        unsigned d01 = cvtpk(S[12],S[13]), d23 = cvtpk(S[14],S[15]);
        unsigned w0,w1,w2,w3,w4,w5,w6,w7;
        swap32(a01, b01, w0, w2);
        swap32(a23, b23, w1, w3);
        swap32(c01, d01, w4, w6);
        swap32(c23, d23, w5, w7);
        const u32x4v A1v = {w0,w1,w2,w3};
        const u32x4v A2v = {w4,w5,w6,w7};
        const bf16x8 A1 = __builtin_bit_cast(bf16x8, A1v);
        const bf16x8 A2 = __builtin_bit_cast(bf16x8, A2v);
        // PV + row-sum accumulate (all on matrix pipe)
        acc = __builtin_amdgcn_mfma_f32_32x32x16_bf16(A1, vf1, acc, 0, 0, 0);
        acc = __builtin_amdgcn_mfma_f32_32x32x16_bf16(A2, vf2, acc, 0, 0, 0);
        acc_sum = __builtin_amdgcn_mfma_f32_32x32x16_bf16(A1, ones, acc_sum, 0, 0, 0);
        acc_sum = __builtin_amdgcn_mfma_f32_32x32x16_bf16(A2, ones, acc_sum, 0, 0, 0);
    }

    // epilogue: acc row q=(r&3)+8*(r>>2)+4*half, col d=l31; acc_sum[r] is the
    // row-sum (identical across lanes) -> per-lane normalize, no shfl.
    #pragma unroll
    for (int r = 0; r < 16; r++) {
        const int q_r = (r & 3) + 8*(r >> 2) + 4*half;
        wagbuf[(size_t)(b*NN + qt + q_r)*CC + h*32 + l31] = f2bf(acc[r] / acc_sum[r]);
    }
}

// ---------------------------------------------------------------------------
// Kernel C: out = (wag * gate) . w_o^T. Barrier-free: a_tile rows wave-private;
// w_o fragment-major (coalesced loads).
// ---------------------------------------------------------------------------
__global__ __launch_bounds__(256) void kernC(
    const u16* __restrict__ wag, const u16* __restrict__ gbuf,
    const u16* __restrict__ wof, float* __restrict__ out)
{
    __shared__ __align__(16) u16 a_tile[64*128];

    const int t = threadIdx.x;
    const int base = blockIdx.x * 64;

    {
        const int rl = t >> 2;
        const int lq = t & 3;
        const u16* src  = wag  + (size_t)(base + rl)*CC + lq*32;
        const u16* gsrc = gbuf + (size_t)(base + rl)*CC + lq*32;
        #pragma unroll
        for (int j8 = 0; j8 < 4; j8++) {
            u16x8 v = *reinterpret_cast<const u16x8*>(src + j8*8);
            u16x8 g = *reinterpret_cast<const u16x8*>(gsrc + j8*8);
            u16x8 pk;
            #pragma unroll
            for (int e = 0; e < 8; e++) pk[e] = f2bf(bf2f(v[e]) * bf2f(g[e]));
            unsigned addr = (unsigned)(rl*256 + (lq*32 + j8*8)*2) ^ (unsigned)((rl & 7) << 4);
            *reinterpret_cast<u16x8*>(reinterpret_cast<char*>(a_tile) + addr) = pk;
        }
    }
    // no barrier: each wave reads only the 16 rows it wrote

    const int wv = t >> 6;
    const int lane = t & 63;
    const int lc = lane & 15;
    const int kg = lane >> 4;

    bf16x8 afr[4];
    {
        const int rA = wv*16 + lc;
        #pragma unroll
        for (int kt = 0; kt < 4; kt++) {
            unsigned addr = (unsigned)(rA*256 + (kt*32 + kg*8)*2) ^ (unsigned)((rA & 7) << 4);
            afr[kt] = *reinterpret_cast<const bf16x8*>(reinterpret_cast<const char*>(a_tile) + addr);
        }
    }
    #pragma unroll
    for (int et = 0; et < 8; et++) {
        f32x4 acc = {0.f,0.f,0.f,0.f};
        #pragma unroll
        for (int kt = 0; kt < 4; kt++) {
            const bf16x8 bw = *reinterpret_cast<const bf16x8*>(
                wof + (size_t)((et*4 + kt)*64 + lane)*8);
            acc = __builtin_amdgcn_mfma_f32_16x16x32_bf16(afr[kt], bw, acc, 0, 0, 0);
        }
        #pragma unroll
        for (int i = 0; i < 4; i++)
            out[(size_t)(base + wv*16 + kg*4 + i)*CC + et*16 + lc] = acc[i];
    }
}

extern "C" void kernel_launch(void* const* d_in, const int* in_sizes, int n_in,
                              void* d_out, int out_size, void* d_ws, size_t ws_size,
                              hipStream_t stream)
{
    const float* pair  = (const float*)d_in[0];
    const int*   mask  = (const int*)d_in[1];
    const float* ln_w  = (const float*)d_in[2];
    const float* ln_b  = (const float*)d_in[3];
    const float* w_bias= (const float*)d_in[4];
    const float* w_q   = (const float*)d_in[5];
    const float* w_k   = (const float*)d_in[6];
    const float* w_v   = (const float*)d_in[7];
    const float* w_g   = (const float*)d_in[8];
    const float* w_o   = (const float*)d_in[9];
    float* out = (float*)d_out;

    char* ws = (char*)d_ws;
    const size_t SZ = (size_t)RR * CC * 2;       // 37,748,736
    u16* qbuf  = (u16*)(ws);
    u16* kfrag = (u16*)(ws + SZ);
    u16* vfrag = (u16*)(ws + 2*SZ);
    u16* gbuf  = (u16*)(ws + 3*SZ);
    float* bfrag = (float*)(ws + 4*SZ);                         // 2,359,296
    char* p = ws + 4*SZ + (size_t)4*RR*4;
    u16* wof  = (u16*)(p);            p += (size_t)CC*CC*2;     // 32 KiB each
    u16* wqf  = (u16*)(p);            p += (size_t)CC*CC*2;
    u16* wkf  = (u16*)(p);            p += (size_t)CC*CC*2;
    u16* wvf  = (u16*)(p);            p += (size_t)CC*CC*2;
    u16* wgf  = (u16*)(p);            p += (size_t)CC*CC*2;
    u16* maskbf = (u16*)(p);          p += (size_t)RR*2;        // 288 KiB
    int* allone = (int*)(p);          p += (size_t)NN*4;        // 1.5 KiB
    const size_t used = (size_t)(p - ws);
    u16* wagbuf = (ws_size >= used + SZ) ? (u16*)(p) : qbuf;

    kernW<<<dim3(992), dim3(256), 0, stream>>>(w_q, w_k, w_v, w_g, w_o, mask,
        wqf, wkf, wvf, wgf, wof, maskbf, allone);
    kernA<<<dim3(RR/64), dim3(256), 0, stream>>>(pair, ln_w, ln_b, w_bias,
        wqf, wkf, wvf, wgf, qbuf, kfrag, vfrag, gbuf, bfrag);
    kernB<<<dim3(4608), dim3(256), 0, stream>>>(qbuf, kfrag, vfrag, bfrag, maskbf, allone, wagbuf);
    kernC<<<dim3(RR/64), dim3(256), 0, stream>>>(wagbuf, gbuf, wof, out);
}